// Round 7
// baseline (1841.962 us; speedup 1.0000x reference)
//
#include <hip/hip_runtime.h>
#include <math.h>

// ---------------------------------------------------------------------------
// ConvLSTM stack, time-skewed pipeline, round 7.
//
// Base = round 5 (1179 us, best). Round-6 atomic pool fusion FAILED (+272 us:
// 2.4M contended L2-RMW atomics/stage >> value of removing cheap drain stages).
//
// Single change vs R5: L2/L3/L4 use CHANNEL-split instead of GATE-split.
// Wave w computes ALL 4 gates for channel group [w*F/4,(w+1)*F/4) of 64 px:
// identical FMA count & block geometry, weights still wave-uniform (SGPR),
// but i,f,c~,o are thread-local -> cell update in registers. Removes the
// LDS gate exchange, __syncthreads, and its 32,640 bank conflicts/stage.
//
// Roles per stage s (32 stages), bid order (longest-latency first):
//   r0: dense ch=s-8 ( 32 blk)   r5: pool1 t=s-1 (497)
//   r1: L4 step t=s-6 ( 85 blk)  r6: pool2 t=s-3 (121)
//   r2: L3 step t=s-4 (421 blk)  r7: pool3 t=s-5 ( 29)
//   r3: L1 step t=s   (993 blk)  r8: pool4 t=s-7 (  7)
//   r4: L2 step t=s-2 (1861 blk)
// ---------------------------------------------------------------------------

static __device__ __forceinline__ float hsig(float x) {
    return fminf(fmaxf(fmaf(0.2f, x, 0.5f), 0.0f), 1.0f);
}
static __device__ __forceinline__ float ftanh(float x) {
    float e = __builtin_amdgcn_exp2f(x * 2.88539008177792681f);
    return 1.0f - 2.0f * __builtin_amdgcn_rcpf(e + 1.0f);
}

// ---- workspace layout (float offsets) ----
constexpr int H1SL = 32 * 126 * 126 * 4;   // 2,032,128
constexpr int H2SL = 32 * 61 * 61 * 8;     //   952,576
constexpr int H3SL = 32 * 29 * 29 * 12;    //   322,944
constexpr int H4SL = 32 * 13 * 13 * 16;    //    86,528
constexpr size_t O_H1 = 0;
constexpr size_t O_H2 = O_H1 + 2 * (size_t)H1SL;
constexpr size_t O_H3 = O_H2 + 2 * (size_t)H2SL;
constexpr size_t O_H4 = O_H3 + 2 * (size_t)H3SL;
constexpr size_t O_C1 = O_H4 + 2 * (size_t)H4SL;
constexpr size_t O_C2 = O_C1 + (size_t)H1SL;
constexpr size_t O_C3 = O_C2 + (size_t)H2SL;
constexpr size_t O_C4 = O_C3 + (size_t)H3SL;
constexpr size_t O_P1 = O_C4 + (size_t)H4SL;
constexpr size_t O_P2 = O_P1 + (size_t)(768 * 63 * 63 * 4);
constexpr size_t O_P3 = O_P2 + (size_t)(768 * 31 * 31 * 8);
constexpr size_t O_P4 = O_P3 + (size_t)(768 * 15 * 15 * 12);
constexpr size_t O_DP = O_P4 + (size_t)(768 * 7 * 7 * 16);
// dense partials: 32 * 24 * 50 floats

__host__ __device__ static inline int role_blocks(int r, int s) {
    int t;
    switch (r) {
    case 0: t = s - 8; return (t >= 0 && t < 24) ? 32   : 0;  // dense chunk
    case 1: t = s - 6; return (t >= 0 && t < 24) ? 85   : 0;  // L4 step
    case 2: t = s - 4; return (t >= 0 && t < 24) ? 421  : 0;  // L3 step
    case 3: t = s;     return (t >= 0 && t < 24) ? 993  : 0;  // L1 step
    case 4: t = s - 2; return (t >= 0 && t < 24) ? 1861 : 0;  // L2 step
    case 5: t = s - 1; return (t >= 0 && t < 24) ? 497  : 0;  // pool1 slice
    case 6: t = s - 3; return (t >= 0 && t < 24) ? 121  : 0;  // pool2 slice
    case 7: t = s - 5; return (t >= 0 && t < 24) ? 29   : 0;  // pool3 slice
    case 8: t = s - 7; return (t >= 0 && t < 24) ? 7    : 0;  // pool4 slice
    }
    return 0;
}
constexpr int NSTAGES = 32;

// ---- L1: merged gates, TWO adjacent pixels (same row) per thread ----
__device__ __forceinline__
void step_pair_d(const float* __restrict__ P,     // (B,T,128,128,3)
                 const float* __restrict__ Wx,    // (3,3,3,16)
                 const float* __restrict__ Wh,    // (3,3,4,16)
                 const float* __restrict__ bias,  // (16)
                 const float* __restrict__ h_prev,// (B,126,126,4) slice
                 float* __restrict__ h_cur,       // (B,126,126,4) slice
                 float* __restrict__ cbuf,        // (B,126,126,4)
                 int t, int lb)
{
    constexpr int CIN = 3, F = 4, HIN = 128, WIN = 128;
    constexpr int B = 32, T = 24, HO = 126, WO = 126, G = 16;
    constexpr int XP = WO / 2;
    constexpr int NPAIR = B * HO * XP;
    const int id = lb * 256 + (int)threadIdx.x;
    if (id >= NPAIR) return;
    const int xp = id % XP;
    const int yy = (id / XP) % HO;
    const int b  = id / (XP * HO);
    const int x0 = 2 * xp;

    float acc[2][4][F];
    #pragma unroll
    for (int u = 0; u < 2; ++u)
        #pragma unroll
        for (int g = 0; g < 4; ++g)
            #pragma unroll
            for (int f = 0; f < F; ++f)
                acc[u][g][f] = bias[g * F + f];

    const float* Pt = P + (size_t)(b * T + t) * HIN * WIN * CIN;
    #pragma unroll
    for (int ky = 0; ky < 3; ++ky) {
        const float* prow = Pt + ((size_t)(yy + ky) * WIN + x0) * CIN;
        float pv[4 * CIN];
        #pragma unroll
        for (int j = 0; j < 2 * CIN; ++j) {
            float2 v2 = reinterpret_cast<const float2*>(prow)[j];
            pv[2 * j] = v2.x; pv[2 * j + 1] = v2.y;
        }
        #pragma unroll
        for (int dx = 0; dx < 4; ++dx)
            #pragma unroll
            for (int ci = 0; ci < CIN; ++ci) {
                const float v = pv[dx * CIN + ci];
                #pragma unroll
                for (int u = 0; u < 2; ++u) {
                    const int kx = dx - u;
                    if (kx >= 0 && kx <= 2) {
                        const float* wr =
                            Wx + (size_t)((ky * 3 + kx) * CIN + ci) * G;
                        #pragma unroll
                        for (int g = 0; g < 4; ++g)
                            #pragma unroll
                            for (int f = 0; f < F; ++f)
                                acc[u][g][f] = fmaf(v, wr[g * F + f], acc[u][g][f]);
                    }
                }
            }
    }

    if (t > 0) {
        #pragma unroll
        for (int ky = 0; ky < 3; ++ky) {
            const int hy = yy + ky - 1;
            if (hy < 0 || hy >= HO) continue;
            const float* hrow = h_prev + ((size_t)b * HO + hy) * WO * F;
            #pragma unroll
            for (int dx = 0; dx < 4; ++dx) {
                const int hx = x0 - 1 + dx;
                if (dx == 0 && x0 == 0) continue;
                if (dx == 3 && hx >= WO) continue;
                const float4* h4 =
                    reinterpret_cast<const float4*>(hrow + (size_t)hx * F);
                float hv[F];
                #pragma unroll
                for (int j = 0; j < F / 4; ++j) {
                    float4 v4 = h4[j];
                    hv[4*j] = v4.x; hv[4*j+1] = v4.y;
                    hv[4*j+2] = v4.z; hv[4*j+3] = v4.w;
                }
                #pragma unroll
                for (int ci = 0; ci < F; ++ci) {
                    const float v = hv[ci];
                    #pragma unroll
                    for (int u = 0; u < 2; ++u) {
                        const int kx = dx - u;
                        if (kx >= 0 && kx <= 2) {
                            const float* wr =
                                Wh + (size_t)((ky * 3 + kx) * F + ci) * G;
                            #pragma unroll
                            for (int g = 0; g < 4; ++g)
                                #pragma unroll
                                for (int f = 0; f < F; ++f)
                                    acc[u][g][f] =
                                        fmaf(v, wr[g * F + f], acc[u][g][f]);
                        }
                    }
                }
            }
        }
    }

    #pragma unroll
    for (int u = 0; u < 2; ++u) {
        const size_t pix = ((size_t)b * HO + yy) * WO + (x0 + u);
        float cn[F], ho[F];
        float* cp = cbuf + pix * F;
        #pragma unroll
        for (int j = 0; j < F / 4; ++j) {
            float4 c4 = (t > 0) ? reinterpret_cast<float4*>(cp)[j]
                                : make_float4(0.f, 0.f, 0.f, 0.f);
            float cold[4] = {c4.x, c4.y, c4.z, c4.w};
            #pragma unroll
            for (int v = 0; v < 4; ++v) {
                const int f = 4 * j + v;
                const float ig = hsig(acc[u][0][f]), fg = hsig(acc[u][1][f]);
                const float cc = ftanh(acc[u][2][f]), og = hsig(acc[u][3][f]);
                cn[f] = fmaf(fg, cold[v], ig * cc);
                ho[f] = og * ftanh(cn[f]);
            }
            reinterpret_cast<float4*>(cp)[j] =
                make_float4(cn[4*j], cn[4*j+1], cn[4*j+2], cn[4*j+3]);
        }
        float* hp = h_cur + pix * F;
        #pragma unroll
        for (int j = 0; j < F / 4; ++j)
            reinterpret_cast<float4*>(hp)[j] =
                make_float4(ho[4*j], ho[4*j+1], ho[4*j+2], ho[4*j+3]);
    }
}

// ---- CHANNEL-split step (L2/L3/L4): wave w = channels [w*F/4,(w+1)*F/4)
//      of 64 pixels, ALL 4 gates in-register. No LDS, no barrier. ----
template<int CIN, int F, int HIN, int WIN>
__device__ __forceinline__
void step_csplit_d(const float* __restrict__ P,    // (B,T,HIN,WIN,CIN) pooled
                   const float* __restrict__ Wx,   // (3,3,CIN,4F)
                   const float* __restrict__ Wh,   // (3,3,F,4F)
                   const float* __restrict__ bias, // (4F)
                   const float* __restrict__ h_prev,// (B,HO,WO,F) slice
                   float* __restrict__ h_cur,
                   float* __restrict__ cbuf,
                   int t, int lb)
{
    constexpr int B = 32, T = 24, HO = HIN - 2, WO = WIN - 2, G = 4 * F;
    constexpr int FH = F / 4;               // channels per wave
    constexpr int NPIX = B * HO * WO;
    const int tid = (int)threadIdx.x, lane = tid & 63;
    const int w = __builtin_amdgcn_readfirstlane(tid >> 6);  // channel group
    const int pix = lb * 64 + lane;
    const bool live = (pix < NPIX);
    const int pp  = live ? pix : NPIX - 1;
    const int sp  = pp % (HO * WO);
    const int b   = pp / (HO * WO);
    const int xx  = sp % WO, yy = sp / WO;

    float acc[4][FH];
    #pragma unroll
    for (int g = 0; g < 4; ++g)
        #pragma unroll
        for (int f = 0; f < FH; ++f)
            acc[g][f] = bias[g * F + w * FH + f];

    const float* Pt = P + (size_t)(b * T + t) * HIN * WIN * CIN;
    #pragma unroll
    for (int ky = 0; ky < 3; ++ky) {
        #pragma unroll
        for (int kx = 0; kx < 3; ++kx) {
            const float* prow = Pt + ((size_t)(yy + ky) * WIN + (xx + kx)) * CIN;
            float pv[CIN];
            #pragma unroll
            for (int j = 0; j < CIN / 4; ++j) {
                float4 v4 = reinterpret_cast<const float4*>(prow)[j];
                pv[4*j] = v4.x; pv[4*j+1] = v4.y; pv[4*j+2] = v4.z; pv[4*j+3] = v4.w;
            }
            #pragma unroll
            for (int ci = 0; ci < CIN; ++ci) {
                const float v = pv[ci];
                const float* wr =
                    Wx + (size_t)((ky * 3 + kx) * CIN + ci) * G + w * FH;
                #pragma unroll
                for (int g = 0; g < 4; ++g)
                    #pragma unroll
                    for (int f = 0; f < FH; ++f)
                        acc[g][f] = fmaf(v, wr[g * F + f], acc[g][f]);
            }
        }
    }

    if (t > 0) {
        const float* Hp = h_prev + (size_t)b * HO * WO * F;
        #pragma unroll
        for (int ky = 0; ky < 3; ++ky) {
            const int hy = yy + ky - 1;
            if (hy < 0 || hy >= HO) continue;
            #pragma unroll
            for (int kx = 0; kx < 3; ++kx) {
                const int hx = xx + kx - 1;
                if (hx < 0 || hx >= WO) continue;
                const float4* h4 = reinterpret_cast<const float4*>(
                    Hp + ((size_t)hy * WO + hx) * F);
                float hv[F];
                #pragma unroll
                for (int j = 0; j < F / 4; ++j) {
                    float4 v4 = h4[j];
                    hv[4*j] = v4.x; hv[4*j+1] = v4.y; hv[4*j+2] = v4.z; hv[4*j+3] = v4.w;
                }
                #pragma unroll
                for (int ci = 0; ci < F; ++ci) {
                    const float v = hv[ci];
                    const float* wr =
                        Wh + (size_t)((ky * 3 + kx) * F + ci) * G + w * FH;
                    #pragma unroll
                    for (int g = 0; g < 4; ++g)
                        #pragma unroll
                        for (int f = 0; f < FH; ++f)
                            acc[g][f] = fmaf(v, wr[g * F + f], acc[g][f]);
                }
            }
        }
    }

    // in-register cell update for this wave's FH channels
    if (live) {
        const size_t base = (size_t)pix * F + w * FH;
        #pragma unroll
        for (int f = 0; f < FH; ++f) {
            const float ig = hsig(acc[0][f]), fg = hsig(acc[1][f]);
            const float cc = ftanh(acc[2][f]), og = hsig(acc[3][f]);
            const float cold = (t > 0) ? cbuf[base + f] : 0.0f;
            const float cnw = fmaf(fg, cold, ig * cc);
            cbuf[base + f] = cnw;
            h_cur[base + f] = og * ftanh(cnw);
        }
    }
}

// ---- MaxPool(2,2,'SAME') of ONE time-slice h -> full pooled buffer at t ----
template<int C, int H, int W, int HP, int WP>
__device__ __forceinline__
void pool_slice_d(const float* __restrict__ h,     // (B,H,W,C) slice
                  float* __restrict__ outF,        // (B,T,HP,WP,C) full
                  int t, int lb)
{
    constexpr int B = 32, T = 24;
    const int idx = lb * 256 + (int)threadIdx.x;
    if (idx >= B * HP * WP) return;
    const int xo = idx % WP;
    const int yo = (idx / WP) % HP;
    const int b  = idx / (WP * HP);
    const int y0 = 2 * yo, x0 = 2 * xo;
    const float* p = h + ((size_t)(b * H + y0) * W + x0) * C;
    float m[C];
    #pragma unroll
    for (int j = 0; j < C / 4; ++j) {
        float4 v = reinterpret_cast<const float4*>(p)[j];
        m[4*j] = v.x; m[4*j+1] = v.y; m[4*j+2] = v.z; m[4*j+3] = v.w;
    }
    if (x0 + 1 < W) {
        const float4* q = reinterpret_cast<const float4*>(p + C);
        #pragma unroll
        for (int j = 0; j < C / 4; ++j) {
            float4 v = q[j];
            m[4*j]   = fmaxf(m[4*j],   v.x); m[4*j+1] = fmaxf(m[4*j+1], v.y);
            m[4*j+2] = fmaxf(m[4*j+2], v.z); m[4*j+3] = fmaxf(m[4*j+3], v.w);
        }
    }
    if (y0 + 1 < H) {
        const float4* q = reinterpret_cast<const float4*>(p + (size_t)W * C);
        #pragma unroll
        for (int j = 0; j < C / 4; ++j) {
            float4 v = q[j];
            m[4*j]   = fmaxf(m[4*j],   v.x); m[4*j+1] = fmaxf(m[4*j+1], v.y);
            m[4*j+2] = fmaxf(m[4*j+2], v.z); m[4*j+3] = fmaxf(m[4*j+3], v.w);
        }
        if (x0 + 1 < W) {
            const float4* q2 = reinterpret_cast<const float4*>(p + (size_t)(W + 1) * C);
            #pragma unroll
            for (int j = 0; j < C / 4; ++j) {
                float4 v = q2[j];
                m[4*j]   = fmaxf(m[4*j],   v.x); m[4*j+1] = fmaxf(m[4*j+1], v.y);
                m[4*j+2] = fmaxf(m[4*j+2], v.z); m[4*j+3] = fmaxf(m[4*j+3], v.w);
            }
        }
    }
    float* o = outF + ((size_t)(b * T + t) * HP * WP + (size_t)yo * WP + xo) * C;
    #pragma unroll
    for (int j = 0; j < C / 4; ++j)
        reinterpret_cast<float4*>(o)[j] =
            make_float4(m[4*j], m[4*j+1], m[4*j+2], m[4*j+3]);
}

// ---- dense partial for one FLAT chunk (= ONE t-slice of pool4, 784 el) ----
__device__ __forceinline__
void dense_partial_d(const float* __restrict__ X, const float* __restrict__ Wd,
                     float* __restrict__ part, int ch, int lb,
                     float* __restrict__ red)
{
    constexpr int FLAT = 18816, K = 50, NC = 24, CHUNK = FLAT / NC; // 784
    const int b = lb;
    const int tid = (int)threadIdx.x, lane = tid & 63, wv = tid >> 6;
    const float* xp = X + (size_t)b * FLAT;
    const int i0 = ch * CHUNK + wv * (CHUNK / 4);   // 196 per wave
    float a0 = 0.f, a1 = 0.f, a2 = 0.f, a3 = 0.f;
    if (lane < K) {
        #pragma unroll 4
        for (int i = i0; i < i0 + CHUNK / 4; i += 4) {
            a0 = fmaf(xp[i + 0], Wd[(size_t)(i + 0) * K + lane], a0);
            a1 = fmaf(xp[i + 1], Wd[(size_t)(i + 1) * K + lane], a1);
            a2 = fmaf(xp[i + 2], Wd[(size_t)(i + 2) * K + lane], a2);
            a3 = fmaf(xp[i + 3], Wd[(size_t)(i + 3) * K + lane], a3);
        }
    }
    red[tid] = (a0 + a1) + (a2 + a3);
    __syncthreads();
    if (tid < 64 && lane < K)
        part[((size_t)b * NC + ch) * K + lane]
            = red[tid] + red[tid + 64] + red[tid + 128] + red[tid + 192];
}

// ---- pipeline stage dispatcher ----
__global__ __launch_bounds__(256)
void pipe_k(const float* __restrict__ x,
            const float* __restrict__ Wx1, const float* __restrict__ Wh1, const float* __restrict__ b1,
            const float* __restrict__ Wx2, const float* __restrict__ Wh2, const float* __restrict__ b2,
            const float* __restrict__ Wx3, const float* __restrict__ Wh3, const float* __restrict__ b3,
            const float* __restrict__ Wx4, const float* __restrict__ Wh4, const float* __restrict__ b4,
            const float* __restrict__ Wd,
            float* __restrict__ ws, int s)
{
    float* h1 = ws + O_H1;  float* h2 = ws + O_H2;
    float* h3 = ws + O_H3;  float* h4 = ws + O_H4;
    float* c1 = ws + O_C1;  float* c2 = ws + O_C2;
    float* c3 = ws + O_C3;  float* c4 = ws + O_C4;
    float* p1 = ws + O_P1;  float* p2 = ws + O_P2;
    float* p3 = ws + O_P3;  float* p4 = ws + O_P4;
    float* dp = ws + O_DP;

    __shared__ float red[256];   // dense reduction only (1 KB)

    int bid = (int)blockIdx.x, r = 0, cum = 0;
    for (; r < 9; ++r) {
        int n = role_blocks(r, s);
        if (bid < cum + n) break;
        cum += n;
    }
    const int lb = bid - cum;

    switch (r) {
    case 0: { const int ch = s - 8;  // dense chunk (longest-latency: FIRST)
        dense_partial_d(p4, Wd, dp, ch, lb, red); } break;
    case 1: { const int t = s - 6;   // L4
        step_csplit_d<12, 16, 15, 15>(p3, Wx4, Wh4, b4,
            h4 + ((t - 1) & 1) * (size_t)H4SL, h4 + (t & 1) * (size_t)H4SL,
            c4, t, lb); } break;
    case 2: { const int t = s - 4;   // L3
        step_csplit_d<8, 12, 31, 31>(p2, Wx3, Wh3, b3,
            h3 + ((t - 1) & 1) * (size_t)H3SL, h3 + (t & 1) * (size_t)H3SL,
            c3, t, lb); } break;
    case 3: { const int t = s;       // L1
        step_pair_d(x, Wx1, Wh1, b1,
            h1 + ((t - 1) & 1) * (size_t)H1SL, h1 + (t & 1) * (size_t)H1SL,
            c1, t, lb); } break;
    case 4: { const int t = s - 2;   // L2
        step_csplit_d<4, 8, 63, 63>(p1, Wx2, Wh2, b2,
            h2 + ((t - 1) & 1) * (size_t)H2SL, h2 + (t & 1) * (size_t)H2SL,
            c2, t, lb); } break;
    case 5: { const int t = s - 1;   // pool1 slice
        pool_slice_d<4, 126, 126, 63, 63>(h1 + (t & 1) * (size_t)H1SL, p1, t, lb); } break;
    case 6: { const int t = s - 3;   // pool2 slice
        pool_slice_d<8, 61, 61, 31, 31>(h2 + (t & 1) * (size_t)H2SL, p2, t, lb); } break;
    case 7: { const int t = s - 5;   // pool3 slice
        pool_slice_d<12, 29, 29, 15, 15>(h3 + (t & 1) * (size_t)H3SL, p3, t, lb); } break;
    case 8: { const int t = s - 7;   // pool4 slice
        pool_slice_d<16, 13, 13, 7, 7>(h4 + (t & 1) * (size_t)H4SL, p4, t, lb); } break;
    }
}

__global__ __launch_bounds__(64)
void dense_finish_k(const float* __restrict__ part, const float* __restrict__ bd,
                    float* __restrict__ out)
{
    constexpr int K = 50, NC = 24;
    const int b = blockIdx.x, lane = threadIdx.x;
    float v = -INFINITY;
    if (lane < K) {
        v = bd[lane];
        #pragma unroll
        for (int c = 0; c < NC; ++c)
            v += part[((size_t)b * NC + c) * K + lane];
    }
    float m = v;
    #pragma unroll
    for (int off = 32; off > 0; off >>= 1) m = fmaxf(m, __shfl_xor(m, off));
    float e = (lane < K) ? __expf(v - m) : 0.0f;
    float sgm = e;
    #pragma unroll
    for (int off = 32; off > 0; off >>= 1) sgm += __shfl_xor(sgm, off);
    if (lane < K) out[(size_t)b * K + lane] = e / sgm;
}

extern "C" void kernel_launch(void* const* d_in, const int* in_sizes, int n_in,
                              void* d_out, int out_size, void* d_ws, size_t ws_size,
                              hipStream_t stream)
{
    const float* x   = (const float*)d_in[0];
    const float* Wx1 = (const float*)d_in[1];
    const float* Wh1 = (const float*)d_in[2];
    const float* b1  = (const float*)d_in[3];
    const float* Wx2 = (const float*)d_in[4];
    const float* Wh2 = (const float*)d_in[5];
    const float* b2  = (const float*)d_in[6];
    const float* Wx3 = (const float*)d_in[7];
    const float* Wh3 = (const float*)d_in[8];
    const float* b3  = (const float*)d_in[9];
    const float* Wx4 = (const float*)d_in[10];
    const float* Wh4 = (const float*)d_in[11];
    const float* b4  = (const float*)d_in[12];
    const float* Wd  = (const float*)d_in[13];
    const float* bd  = (const float*)d_in[14];
    float* out = (float*)d_out;
    float* ws  = (float*)d_ws;

    for (int s = 0; s < NSTAGES; ++s) {
        int nb = 0;
        for (int r = 0; r < 9; ++r) nb += role_blocks(r, s);
        pipe_k<<<nb, 256, 0, stream>>>(x,
                                       Wx1, Wh1, b1, Wx2, Wh2, b2,
                                       Wx3, Wh3, b3, Wx4, Wh4, b4,
                                       Wd, ws, s);
    }
    dense_finish_k<<<32, 64, 0, stream>>>(ws + O_DP, bd, out);
}

// Round 8
// 1168.661 us; speedup vs baseline: 1.5761x; 1.5761x over previous
//
#include <hip/hip_runtime.h>
#include <math.h>

// ---------------------------------------------------------------------------
// ConvLSTM stack, time-skewed pipeline, round 8.
//
// Base = round 5 (1179 us, best). R6 atomic pools FAILED (+272: contended
// RMW). R7 channel-split FAILED (+663: strided scalar weight loads broke
// s_load_dwordx batching; scattered epilogue). Lesson: gate-split's
// contiguous wave-uniform weight rows + coalesced LDS epilogue are
// load-bearing.
//
// Single change vs R5: L2 uses gate-PAIR split. Block = 128 pixels;
// wave w handles gate pair (tid>>7) for 64 px. Weight row = contiguous
// 2F floats (s_load-friendly), FMA/thread x2 (1728 < L1's 2016),
// window loads per pixel halved, LDS exchange kept (16 KB unchanged).
// L2 waves/stage 7444 -> 3724 (stage total ~16K -> ~12.5K).
//
// Roles per stage s (32 stages), bid order (longest-latency first):
//   r0: dense ch=s-8 ( 32 blk)   r5: pool1 t=s-1 (497)
//   r1: L4 step t=s-6 ( 85 blk)  r6: pool2 t=s-3 (121)
//   r2: L3 step t=s-4 (421 blk)  r7: pool3 t=s-5 ( 29)
//   r3: L1 step t=s   (993 blk)  r8: pool4 t=s-7 (  7)
//   r4: L2 step t=s-2 ( 931 blk, gate-pair)
// ---------------------------------------------------------------------------

static __device__ __forceinline__ float hsig(float x) {
    return fminf(fmaxf(fmaf(0.2f, x, 0.5f), 0.0f), 1.0f);
}
static __device__ __forceinline__ float ftanh(float x) {
    float e = __builtin_amdgcn_exp2f(x * 2.88539008177792681f);
    return 1.0f - 2.0f * __builtin_amdgcn_rcpf(e + 1.0f);
}

// ---- workspace layout (float offsets) ----
constexpr int H1SL = 32 * 126 * 126 * 4;   // 2,032,128
constexpr int H2SL = 32 * 61 * 61 * 8;     //   952,576
constexpr int H3SL = 32 * 29 * 29 * 12;    //   322,944
constexpr int H4SL = 32 * 13 * 13 * 16;    //    86,528
constexpr size_t O_H1 = 0;
constexpr size_t O_H2 = O_H1 + 2 * (size_t)H1SL;
constexpr size_t O_H3 = O_H2 + 2 * (size_t)H2SL;
constexpr size_t O_H4 = O_H3 + 2 * (size_t)H3SL;
constexpr size_t O_C1 = O_H4 + 2 * (size_t)H4SL;
constexpr size_t O_C2 = O_C1 + (size_t)H1SL;
constexpr size_t O_C3 = O_C2 + (size_t)H2SL;
constexpr size_t O_C4 = O_C3 + (size_t)H3SL;
constexpr size_t O_P1 = O_C4 + (size_t)H4SL;
constexpr size_t O_P2 = O_P1 + (size_t)(768 * 63 * 63 * 4);
constexpr size_t O_P3 = O_P2 + (size_t)(768 * 31 * 31 * 8);
constexpr size_t O_P4 = O_P3 + (size_t)(768 * 15 * 15 * 12);
constexpr size_t O_DP = O_P4 + (size_t)(768 * 7 * 7 * 16);
// dense partials: 32 * 24 * 50 floats

__host__ __device__ static inline int role_blocks(int r, int s) {
    int t;
    switch (r) {
    case 0: t = s - 8; return (t >= 0 && t < 24) ? 32   : 0;  // dense chunk
    case 1: t = s - 6; return (t >= 0 && t < 24) ? 85   : 0;  // L4 step
    case 2: t = s - 4; return (t >= 0 && t < 24) ? 421  : 0;  // L3 step
    case 3: t = s;     return (t >= 0 && t < 24) ? 993  : 0;  // L1 step
    case 4: t = s - 2; return (t >= 0 && t < 24) ? 931  : 0;  // L2 step (pair)
    case 5: t = s - 1; return (t >= 0 && t < 24) ? 497  : 0;  // pool1 slice
    case 6: t = s - 3; return (t >= 0 && t < 24) ? 121  : 0;  // pool2 slice
    case 7: t = s - 5; return (t >= 0 && t < 24) ? 29   : 0;  // pool3 slice
    case 8: t = s - 7; return (t >= 0 && t < 24) ? 7    : 0;  // pool4 slice
    }
    return 0;
}
constexpr int NSTAGES = 32;

// ---- L1: merged gates, TWO adjacent pixels (same row) per thread ----
__device__ __forceinline__
void step_pair_d(const float* __restrict__ P,     // (B,T,128,128,3)
                 const float* __restrict__ Wx,    // (3,3,3,16)
                 const float* __restrict__ Wh,    // (3,3,4,16)
                 const float* __restrict__ bias,  // (16)
                 const float* __restrict__ h_prev,// (B,126,126,4) slice
                 float* __restrict__ h_cur,       // (B,126,126,4) slice
                 float* __restrict__ cbuf,        // (B,126,126,4)
                 int t, int lb)
{
    constexpr int CIN = 3, F = 4, HIN = 128, WIN = 128;
    constexpr int B = 32, T = 24, HO = 126, WO = 126, G = 16;
    constexpr int XP = WO / 2;
    constexpr int NPAIR = B * HO * XP;
    const int id = lb * 256 + (int)threadIdx.x;
    if (id >= NPAIR) return;
    const int xp = id % XP;
    const int yy = (id / XP) % HO;
    const int b  = id / (XP * HO);
    const int x0 = 2 * xp;

    float acc[2][4][F];
    #pragma unroll
    for (int u = 0; u < 2; ++u)
        #pragma unroll
        for (int g = 0; g < 4; ++g)
            #pragma unroll
            for (int f = 0; f < F; ++f)
                acc[u][g][f] = bias[g * F + f];

    const float* Pt = P + (size_t)(b * T + t) * HIN * WIN * CIN;
    #pragma unroll
    for (int ky = 0; ky < 3; ++ky) {
        const float* prow = Pt + ((size_t)(yy + ky) * WIN + x0) * CIN;
        float pv[4 * CIN];
        #pragma unroll
        for (int j = 0; j < 2 * CIN; ++j) {
            float2 v2 = reinterpret_cast<const float2*>(prow)[j];
            pv[2 * j] = v2.x; pv[2 * j + 1] = v2.y;
        }
        #pragma unroll
        for (int dx = 0; dx < 4; ++dx)
            #pragma unroll
            for (int ci = 0; ci < CIN; ++ci) {
                const float v = pv[dx * CIN + ci];
                #pragma unroll
                for (int u = 0; u < 2; ++u) {
                    const int kx = dx - u;
                    if (kx >= 0 && kx <= 2) {
                        const float* wr =
                            Wx + (size_t)((ky * 3 + kx) * CIN + ci) * G;
                        #pragma unroll
                        for (int g = 0; g < 4; ++g)
                            #pragma unroll
                            for (int f = 0; f < F; ++f)
                                acc[u][g][f] = fmaf(v, wr[g * F + f], acc[u][g][f]);
                    }
                }
            }
    }

    if (t > 0) {
        #pragma unroll
        for (int ky = 0; ky < 3; ++ky) {
            const int hy = yy + ky - 1;
            if (hy < 0 || hy >= HO) continue;
            const float* hrow = h_prev + ((size_t)b * HO + hy) * WO * F;
            #pragma unroll
            for (int dx = 0; dx < 4; ++dx) {
                const int hx = x0 - 1 + dx;
                if (dx == 0 && x0 == 0) continue;
                if (dx == 3 && hx >= WO) continue;
                const float4* h4 =
                    reinterpret_cast<const float4*>(hrow + (size_t)hx * F);
                float hv[F];
                #pragma unroll
                for (int j = 0; j < F / 4; ++j) {
                    float4 v4 = h4[j];
                    hv[4*j] = v4.x; hv[4*j+1] = v4.y;
                    hv[4*j+2] = v4.z; hv[4*j+3] = v4.w;
                }
                #pragma unroll
                for (int ci = 0; ci < F; ++ci) {
                    const float v = hv[ci];
                    #pragma unroll
                    for (int u = 0; u < 2; ++u) {
                        const int kx = dx - u;
                        if (kx >= 0 && kx <= 2) {
                            const float* wr =
                                Wh + (size_t)((ky * 3 + kx) * F + ci) * G;
                            #pragma unroll
                            for (int g = 0; g < 4; ++g)
                                #pragma unroll
                                for (int f = 0; f < F; ++f)
                                    acc[u][g][f] =
                                        fmaf(v, wr[g * F + f], acc[u][g][f]);
                        }
                    }
                }
            }
        }
    }

    #pragma unroll
    for (int u = 0; u < 2; ++u) {
        const size_t pix = ((size_t)b * HO + yy) * WO + (x0 + u);
        float cn[F], ho[F];
        float* cp = cbuf + pix * F;
        #pragma unroll
        for (int j = 0; j < F / 4; ++j) {
            float4 c4 = (t > 0) ? reinterpret_cast<float4*>(cp)[j]
                                : make_float4(0.f, 0.f, 0.f, 0.f);
            float cold[4] = {c4.x, c4.y, c4.z, c4.w};
            #pragma unroll
            for (int v = 0; v < 4; ++v) {
                const int f = 4 * j + v;
                const float ig = hsig(acc[u][0][f]), fg = hsig(acc[u][1][f]);
                const float cc = ftanh(acc[u][2][f]), og = hsig(acc[u][3][f]);
                cn[f] = fmaf(fg, cold[v], ig * cc);
                ho[f] = og * ftanh(cn[f]);
            }
            reinterpret_cast<float4*>(cp)[j] =
                make_float4(cn[4*j], cn[4*j+1], cn[4*j+2], cn[4*j+3]);
        }
        float* hp = h_cur + pix * F;
        #pragma unroll
        for (int j = 0; j < F / 4; ++j)
            reinterpret_cast<float4*>(hp)[j] =
                make_float4(ho[4*j], ho[4*j+1], ho[4*j+2], ho[4*j+3]);
    }
}

// ---- gate-split step (L3/L4): wave w = gate w of 64 pixels ----
template<int CIN, int F, int HIN, int WIN>
__device__ __forceinline__
void step_split_d(const float* __restrict__ P,     // (B,T,HIN,WIN,CIN) pooled
                  const float* __restrict__ Wx,
                  const float* __restrict__ Wh,
                  const float* __restrict__ bias,
                  const float* __restrict__ h_prev,// (B,HO,WO,F) slice
                  float* __restrict__ h_cur,
                  float* __restrict__ cbuf,
                  int t, int lb, float* __restrict__ gb)
{
    constexpr int B = 32, T = 24, HO = HIN - 2, WO = WIN - 2, G = 4 * F;
    constexpr int NPIX = B * HO * WO;
    const int tid = (int)threadIdx.x, lane = tid & 63;
    const int w = __builtin_amdgcn_readfirstlane(tid >> 6);
    const int pix = lb * 64 + lane;
    const int pp  = (pix < NPIX) ? pix : NPIX - 1;
    const int sp  = pp % (HO * WO);
    const int b   = pp / (HO * WO);
    const int xx  = sp % WO, yy = sp / WO;

    float acc[F];
    #pragma unroll
    for (int f = 0; f < F; ++f) acc[f] = bias[w * F + f];

    const float* Pt = P + (size_t)(b * T + t) * HIN * WIN * CIN;
    #pragma unroll
    for (int ky = 0; ky < 3; ++ky) {
        #pragma unroll
        for (int kx = 0; kx < 3; ++kx) {
            const float* prow = Pt + ((size_t)(yy + ky) * WIN + (xx + kx)) * CIN;
            float pv[CIN];
            #pragma unroll
            for (int j = 0; j < CIN / 4; ++j) {
                float4 v4 = reinterpret_cast<const float4*>(prow)[j];
                pv[4*j] = v4.x; pv[4*j+1] = v4.y; pv[4*j+2] = v4.z; pv[4*j+3] = v4.w;
            }
            #pragma unroll
            for (int ci = 0; ci < CIN; ++ci) {
                const float v = pv[ci];
                const float* wr = Wx + (size_t)((ky * 3 + kx) * CIN + ci) * G + w * F;
                #pragma unroll
                for (int f = 0; f < F; ++f)
                    acc[f] = fmaf(v, wr[f], acc[f]);
            }
        }
    }

    if (t > 0) {
        const float* Hp = h_prev + (size_t)b * HO * WO * F;
        #pragma unroll
        for (int ky = 0; ky < 3; ++ky) {
            const int hy = yy + ky - 1;
            if (hy < 0 || hy >= HO) continue;
            #pragma unroll
            for (int kx = 0; kx < 3; ++kx) {
                const int hx = xx + kx - 1;
                if (hx < 0 || hx >= WO) continue;
                const float4* h4 = reinterpret_cast<const float4*>(
                    Hp + ((size_t)hy * WO + hx) * F);
                float hv[F];
                #pragma unroll
                for (int j = 0; j < F / 4; ++j) {
                    float4 v4 = h4[j];
                    hv[4*j] = v4.x; hv[4*j+1] = v4.y; hv[4*j+2] = v4.z; hv[4*j+3] = v4.w;
                }
                #pragma unroll
                for (int ci = 0; ci < F; ++ci) {
                    const float v = hv[ci];
                    const float* wr = Wh + (size_t)((ky * 3 + kx) * F + ci) * G + w * F;
                    #pragma unroll
                    for (int f = 0; f < F; ++f)
                        acc[f] = fmaf(v, wr[f], acc[f]);
                }
            }
        }
    }

    #pragma unroll
    for (int f = 0; f < F; ++f) gb[w * (64 * F) + lane * F + f] = acc[f];
    __syncthreads();

    #pragma unroll
    for (int r2 = 0; r2 < F / 4; ++r2) {
        const int it = r2 * 256 + tid;
        const int pl = it / F, fo = it % F;
        const int pix2 = lb * 64 + pl;
        if (pix2 < NPIX) {
            const float ig = hsig(gb[0 * (64*F) + it]), fg = hsig(gb[1 * (64*F) + it]);
            const float cc = ftanh(gb[2 * (64*F) + it]), og = hsig(gb[3 * (64*F) + it]);
            const size_t cix = (size_t)pix2 * F + fo;
            const float cold = (t > 0) ? cbuf[cix] : 0.0f;
            const float cnw = fmaf(fg, cold, ig * cc);
            cbuf[cix] = cnw;
            h_cur[cix] = og * ftanh(cnw);
        }
    }
}

// ---- L2: gate-PAIR split. Block = 128 px; wave w: gate pair (w>>1) for
//      64 px (group w&1). Weight rows contiguous 2F floats (SGPR-friendly);
//      LDS exchange + coalesced epilogue retained. ----
template<int CIN, int F, int HIN, int WIN>
__device__ __forceinline__
void step_split2_d(const float* __restrict__ P,     // (B,T,HIN,WIN,CIN) pooled
                   const float* __restrict__ Wx,    // (3,3,CIN,4F)
                   const float* __restrict__ Wh,    // (3,3,F,4F)
                   const float* __restrict__ bias,  // (4F)
                   const float* __restrict__ h_prev,// (B,HO,WO,F) slice
                   float* __restrict__ h_cur,
                   float* __restrict__ cbuf,
                   int t, int lb, float* __restrict__ gb)
{
    constexpr int B = 32, T = 24, HO = HIN - 2, WO = WIN - 2, G = 4 * F;
    constexpr int NPIX = B * HO * WO;
    constexpr int F2 = 2 * F;
    const int tid = (int)threadIdx.x, lane = tid & 63;
    const int wv = tid >> 6;
    const int gp = __builtin_amdgcn_readfirstlane(tid >> 7);  // gate pair 0/1
    const int pl = (wv & 1) * 64 + lane;                      // 0..127
    const int pix = lb * 128 + pl;
    const int pp  = (pix < NPIX) ? pix : NPIX - 1;
    const int sp  = pp % (HO * WO);
    const int b   = pp / (HO * WO);
    const int xx  = sp % WO, yy = sp / WO;

    float acc[2][F];                       // gates (2gp, 2gp+1)
    #pragma unroll
    for (int g2 = 0; g2 < 2; ++g2)
        #pragma unroll
        for (int f = 0; f < F; ++f)
            acc[g2][f] = bias[gp * F2 + g2 * F + f];

    const float* Pt = P + (size_t)(b * T + t) * HIN * WIN * CIN;
    #pragma unroll
    for (int ky = 0; ky < 3; ++ky) {
        #pragma unroll
        for (int kx = 0; kx < 3; ++kx) {
            const float* prow = Pt + ((size_t)(yy + ky) * WIN + (xx + kx)) * CIN;
            float pv[CIN];
            #pragma unroll
            for (int j = 0; j < CIN / 4; ++j) {
                float4 v4 = reinterpret_cast<const float4*>(prow)[j];
                pv[4*j] = v4.x; pv[4*j+1] = v4.y; pv[4*j+2] = v4.z; pv[4*j+3] = v4.w;
            }
            #pragma unroll
            for (int ci = 0; ci < CIN; ++ci) {
                const float v = pv[ci];
                const float* wr =
                    Wx + (size_t)((ky * 3 + kx) * CIN + ci) * G + gp * F2;
                #pragma unroll
                for (int g2 = 0; g2 < 2; ++g2)
                    #pragma unroll
                    for (int f = 0; f < F; ++f)
                        acc[g2][f] = fmaf(v, wr[g2 * F + f], acc[g2][f]);
            }
        }
    }

    if (t > 0) {
        const float* Hp = h_prev + (size_t)b * HO * WO * F;
        #pragma unroll
        for (int ky = 0; ky < 3; ++ky) {
            const int hy = yy + ky - 1;
            if (hy < 0 || hy >= HO) continue;
            #pragma unroll
            for (int kx = 0; kx < 3; ++kx) {
                const int hx = xx + kx - 1;
                if (hx < 0 || hx >= WO) continue;
                const float4* h4 = reinterpret_cast<const float4*>(
                    Hp + ((size_t)hy * WO + hx) * F);
                float hv[F];
                #pragma unroll
                for (int j = 0; j < F / 4; ++j) {
                    float4 v4 = h4[j];
                    hv[4*j] = v4.x; hv[4*j+1] = v4.y; hv[4*j+2] = v4.z; hv[4*j+3] = v4.w;
                }
                #pragma unroll
                for (int ci = 0; ci < F; ++ci) {
                    const float v = hv[ci];
                    const float* wr =
                        Wh + (size_t)((ky * 3 + kx) * F + ci) * G + gp * F2;
                    #pragma unroll
                    for (int g2 = 0; g2 < 2; ++g2)
                        #pragma unroll
                        for (int f = 0; f < F; ++f)
                            acc[g2][f] = fmaf(v, wr[g2 * F + f], acc[g2][f]);
                }
            }
        }
    }

    // gb layout: [gp][pl][2F] -> thread stores 2F contiguous floats
    #pragma unroll
    for (int j = 0; j < F2; ++j)
        gb[(gp * 128 + pl) * F2 + j] = acc[j / F][j % F];
    __syncthreads();

    // cell update: 128*F items / 256 threads = F/2 iters, coalesced
    #pragma unroll
    for (int r2 = 0; r2 < F / 2; ++r2) {
        const int it = r2 * 256 + tid;
        const int p2 = it / F, fo = it % F;
        const int pix2 = lb * 128 + p2;
        if (pix2 < NPIX) {
            const float ig = hsig(gb[(0 * 128 + p2) * F2 + fo]);
            const float fg = hsig(gb[(0 * 128 + p2) * F2 + F + fo]);
            const float cc = ftanh(gb[(1 * 128 + p2) * F2 + fo]);
            const float og = hsig(gb[(1 * 128 + p2) * F2 + F + fo]);
            const size_t cix = (size_t)pix2 * F + fo;
            const float cold = (t > 0) ? cbuf[cix] : 0.0f;
            const float cnw = fmaf(fg, cold, ig * cc);
            cbuf[cix] = cnw;
            h_cur[cix] = og * ftanh(cnw);
        }
    }
}

// ---- MaxPool(2,2,'SAME') of ONE time-slice h -> full pooled buffer at t ----
template<int C, int H, int W, int HP, int WP>
__device__ __forceinline__
void pool_slice_d(const float* __restrict__ h,     // (B,H,W,C) slice
                  float* __restrict__ outF,        // (B,T,HP,WP,C) full
                  int t, int lb)
{
    constexpr int B = 32, T = 24;
    const int idx = lb * 256 + (int)threadIdx.x;
    if (idx >= B * HP * WP) return;
    const int xo = idx % WP;
    const int yo = (idx / WP) % HP;
    const int b  = idx / (WP * HP);
    const int y0 = 2 * yo, x0 = 2 * xo;
    const float* p = h + ((size_t)(b * H + y0) * W + x0) * C;
    float m[C];
    #pragma unroll
    for (int j = 0; j < C / 4; ++j) {
        float4 v = reinterpret_cast<const float4*>(p)[j];
        m[4*j] = v.x; m[4*j+1] = v.y; m[4*j+2] = v.z; m[4*j+3] = v.w;
    }
    if (x0 + 1 < W) {
        const float4* q = reinterpret_cast<const float4*>(p + C);
        #pragma unroll
        for (int j = 0; j < C / 4; ++j) {
            float4 v = q[j];
            m[4*j]   = fmaxf(m[4*j],   v.x); m[4*j+1] = fmaxf(m[4*j+1], v.y);
            m[4*j+2] = fmaxf(m[4*j+2], v.z); m[4*j+3] = fmaxf(m[4*j+3], v.w);
        }
    }
    if (y0 + 1 < H) {
        const float4* q = reinterpret_cast<const float4*>(p + (size_t)W * C);
        #pragma unroll
        for (int j = 0; j < C / 4; ++j) {
            float4 v = q[j];
            m[4*j]   = fmaxf(m[4*j],   v.x); m[4*j+1] = fmaxf(m[4*j+1], v.y);
            m[4*j+2] = fmaxf(m[4*j+2], v.z); m[4*j+3] = fmaxf(m[4*j+3], v.w);
        }
        if (x0 + 1 < W) {
            const float4* q2 = reinterpret_cast<const float4*>(p + (size_t)(W + 1) * C);
            #pragma unroll
            for (int j = 0; j < C / 4; ++j) {
                float4 v = q2[j];
                m[4*j]   = fmaxf(m[4*j],   v.x); m[4*j+1] = fmaxf(m[4*j+1], v.y);
                m[4*j+2] = fmaxf(m[4*j+2], v.z); m[4*j+3] = fmaxf(m[4*j+3], v.w);
            }
        }
    }
    float* o = outF + ((size_t)(b * T + t) * HP * WP + (size_t)yo * WP + xo) * C;
    #pragma unroll
    for (int j = 0; j < C / 4; ++j)
        reinterpret_cast<float4*>(o)[j] =
            make_float4(m[4*j], m[4*j+1], m[4*j+2], m[4*j+3]);
}

// ---- dense partial for one FLAT chunk (= ONE t-slice of pool4, 784 el) ----
__device__ __forceinline__
void dense_partial_d(const float* __restrict__ X, const float* __restrict__ Wd,
                     float* __restrict__ part, int ch, int lb,
                     float* __restrict__ red)
{
    constexpr int FLAT = 18816, K = 50, NC = 24, CHUNK = FLAT / NC; // 784
    const int b = lb;
    const int tid = (int)threadIdx.x, lane = tid & 63, wv = tid >> 6;
    const float* xp = X + (size_t)b * FLAT;
    const int i0 = ch * CHUNK + wv * (CHUNK / 4);   // 196 per wave
    float a0 = 0.f, a1 = 0.f, a2 = 0.f, a3 = 0.f;
    if (lane < K) {
        #pragma unroll 4
        for (int i = i0; i < i0 + CHUNK / 4; i += 4) {
            a0 = fmaf(xp[i + 0], Wd[(size_t)(i + 0) * K + lane], a0);
            a1 = fmaf(xp[i + 1], Wd[(size_t)(i + 1) * K + lane], a1);
            a2 = fmaf(xp[i + 2], Wd[(size_t)(i + 2) * K + lane], a2);
            a3 = fmaf(xp[i + 3], Wd[(size_t)(i + 3) * K + lane], a3);
        }
    }
    red[tid] = (a0 + a1) + (a2 + a3);
    __syncthreads();
    if (tid < 64 && lane < K)
        part[((size_t)b * NC + ch) * K + lane]
            = red[tid] + red[tid + 64] + red[tid + 128] + red[tid + 192];
}

// ---- pipeline stage dispatcher ----
__global__ __launch_bounds__(256)
void pipe_k(const float* __restrict__ x,
            const float* __restrict__ Wx1, const float* __restrict__ Wh1, const float* __restrict__ b1,
            const float* __restrict__ Wx2, const float* __restrict__ Wh2, const float* __restrict__ b2,
            const float* __restrict__ Wx3, const float* __restrict__ Wh3, const float* __restrict__ b3,
            const float* __restrict__ Wx4, const float* __restrict__ Wh4, const float* __restrict__ b4,
            const float* __restrict__ Wd,
            float* __restrict__ ws, int s)
{
    float* h1 = ws + O_H1;  float* h2 = ws + O_H2;
    float* h3 = ws + O_H3;  float* h4 = ws + O_H4;
    float* c1 = ws + O_C1;  float* c2 = ws + O_C2;
    float* c3 = ws + O_C3;  float* c4 = ws + O_C4;
    float* p1 = ws + O_P1;  float* p2 = ws + O_P2;
    float* p3 = ws + O_P3;  float* p4 = ws + O_P4;
    float* dp = ws + O_DP;

    __shared__ float gb[4 * 64 * 16];   // 16 KB: split gate buf / dense red

    int bid = (int)blockIdx.x, r = 0, cum = 0;
    for (; r < 9; ++r) {
        int n = role_blocks(r, s);
        if (bid < cum + n) break;
        cum += n;
    }
    const int lb = bid - cum;

    switch (r) {
    case 0: { const int ch = s - 8;  // dense chunk (longest-latency: FIRST)
        dense_partial_d(p4, Wd, dp, ch, lb, gb); } break;
    case 1: { const int t = s - 6;   // L4
        step_split_d<12, 16, 15, 15>(p3, Wx4, Wh4, b4,
            h4 + ((t - 1) & 1) * (size_t)H4SL, h4 + (t & 1) * (size_t)H4SL,
            c4, t, lb, gb); } break;
    case 2: { const int t = s - 4;   // L3
        step_split_d<8, 12, 31, 31>(p2, Wx3, Wh3, b3,
            h3 + ((t - 1) & 1) * (size_t)H3SL, h3 + (t & 1) * (size_t)H3SL,
            c3, t, lb, gb); } break;
    case 3: { const int t = s;       // L1
        step_pair_d(x, Wx1, Wh1, b1,
            h1 + ((t - 1) & 1) * (size_t)H1SL, h1 + (t & 1) * (size_t)H1SL,
            c1, t, lb); } break;
    case 4: { const int t = s - 2;   // L2 (gate-pair, 128 px/block)
        step_split2_d<4, 8, 63, 63>(p1, Wx2, Wh2, b2,
            h2 + ((t - 1) & 1) * (size_t)H2SL, h2 + (t & 1) * (size_t)H2SL,
            c2, t, lb, gb); } break;
    case 5: { const int t = s - 1;   // pool1 slice
        pool_slice_d<4, 126, 126, 63, 63>(h1 + (t & 1) * (size_t)H1SL, p1, t, lb); } break;
    case 6: { const int t = s - 3;   // pool2 slice
        pool_slice_d<8, 61, 61, 31, 31>(h2 + (t & 1) * (size_t)H2SL, p2, t, lb); } break;
    case 7: { const int t = s - 5;   // pool3 slice
        pool_slice_d<12, 29, 29, 15, 15>(h3 + (t & 1) * (size_t)H3SL, p3, t, lb); } break;
    case 8: { const int t = s - 7;   // pool4 slice
        pool_slice_d<16, 13, 13, 7, 7>(h4 + (t & 1) * (size_t)H4SL, p4, t, lb); } break;
    }
}

__global__ __launch_bounds__(64)
void dense_finish_k(const float* __restrict__ part, const float* __restrict__ bd,
                    float* __restrict__ out)
{
    constexpr int K = 50, NC = 24;
    const int b = blockIdx.x, lane = threadIdx.x;
    float v = -INFINITY;
    if (lane < K) {
        v = bd[lane];
        #pragma unroll
        for (int c = 0; c < NC; ++c)
            v += part[((size_t)b * NC + c) * K + lane];
    }
    float m = v;
    #pragma unroll
    for (int off = 32; off > 0; off >>= 1) m = fmaxf(m, __shfl_xor(m, off));
    float e = (lane < K) ? __expf(v - m) : 0.0f;
    float sgm = e;
    #pragma unroll
    for (int off = 32; off > 0; off >>= 1) sgm += __shfl_xor(sgm, off);
    if (lane < K) out[(size_t)b * K + lane] = e / sgm;
}

extern "C" void kernel_launch(void* const* d_in, const int* in_sizes, int n_in,
                              void* d_out, int out_size, void* d_ws, size_t ws_size,
                              hipStream_t stream)
{
    const float* x   = (const float*)d_in[0];
    const float* Wx1 = (const float*)d_in[1];
    const float* Wh1 = (const float*)d_in[2];
    const float* b1  = (const float*)d_in[3];
    const float* Wx2 = (const float*)d_in[4];
    const float* Wh2 = (const float*)d_in[5];
    const float* b2  = (const float*)d_in[6];
    const float* Wx3 = (const float*)d_in[7];
    const float* Wh3 = (const float*)d_in[8];
    const float* b3  = (const float*)d_in[9];
    const float* Wx4 = (const float*)d_in[10];
    const float* Wh4 = (const float*)d_in[11];
    const float* b4  = (const float*)d_in[12];
    const float* Wd  = (const float*)d_in[13];
    const float* bd  = (const float*)d_in[14];
    float* out = (float*)d_out;
    float* ws  = (float*)d_ws;

    for (int s = 0; s < NSTAGES; ++s) {
        int nb = 0;
        for (int r = 0; r < 9; ++r) nb += role_blocks(r, s);
        pipe_k<<<nb, 256, 0, stream>>>(x,
                                       Wx1, Wh1, b1, Wx2, Wh2, b2,
                                       Wx3, Wh3, b3, Wx4, Wh4, b4,
                                       Wd, ws, s);
    }
    dense_finish_k<<<32, 64, 0, stream>>>(ws + O_DP, bd, out);
}